// Round 3
// baseline (1058.951 us; speedup 1.0000x reference)
//
#include <hip/hip_runtime.h>
#include <hip/hip_bf16.h>

#define NN 50000
#define NE 800000
#define NB 5000
#define ND 32
#define EDD 16
#define HDD 64
#define H 128
#define ETOT (NE + NN)
#define NEG 0.2f
#define EPS_LN 1e-5f

__device__ __forceinline__ float siluf(float x){ return x / (1.f + __expf(-x)); }

__device__ __forceinline__ float wsum(float v){
  v += __shfl_xor(v, 32, 64);
  v += __shfl_xor(v, 16, 64);
  v += __shfl_xor(v, 8, 64);
  v += __shfl_xor(v, 4, 64);
  v += __shfl_xor(v, 2, 64);
  v += __shfl_xor(v, 1, 64);
  return v;
}

// LayerNorm across a 128-thread block (one row), j = threadIdx.x
__device__ __forceinline__ float blockLN128(float x, const float* g, const float* b, int j, float* red){
  int lane = j & 63, wid = j >> 6;
  float s = wsum(x);
  if (lane == 0) red[wid] = s;
  __syncthreads();
  float mu = (red[0] + red[1]) * 0.0078125f;
  float d = x - mu;
  float s2 = wsum(d * d);
  if (lane == 0) red[2 + wid] = s2;
  __syncthreads();
  float var = (red[2] + red[3]) * 0.0078125f;
  return d * (1.f / sqrtf(var + EPS_LN)) * g[j] + b[j];
}

// ---------------- household encoder ----------------
__global__ __launch_bounds__(128) void k_house(const float* __restrict__ hf,
    const float* __restrict__ hW1, const float* __restrict__ hb1,
    const float* __restrict__ hg1, const float* __restrict__ hB1,
    const float* __restrict__ hW2, const float* __restrict__ hb2,
    const float* __restrict__ hg2, const float* __restrict__ hB2,
    float* __restrict__ hout){
  __shared__ float sin_[HDD];
  __shared__ float smid[H];
  __shared__ float red[4];
  int bidx = blockIdx.x, j = threadIdx.x;
  if (j < HDD) sin_[j] = hf[bidx * HDD + j];
  __syncthreads();
  float acc = hb1[j];
  #pragma unroll
  for (int k = 0; k < HDD; k++) acc += sin_[k] * hW1[k * H + j];
  float v = siluf(blockLN128(acc, hg1, hB1, j, red));
  __syncthreads();
  smid[j] = v;
  __syncthreads();
  float acc2 = hb2[j];
  #pragma unroll
  for (int k = 0; k < H; k++) acc2 += smid[k] * hW2[k * H + j];
  float v2 = siluf(blockLN128(acc2, hg2, hB2, j, red));
  hout[bidx * H + j] = v2;
}

// ---------------- time embedding table (t in [0,1000)) ----------------
__global__ __launch_bounds__(128) void k_temb(const float* __restrict__ tW1, const float* __restrict__ tb1,
    const float* __restrict__ tW2, const float* __restrict__ tb2, float* __restrict__ table){
  __shared__ float smid[H];
  int bidx = blockIdx.x, j = threadIdx.x;
  float tv = (float)bidx;
  smid[j] = siluf(tv * tW1[j] + tb1[j]);
  __syncthreads();
  float acc = tb2[j];
  #pragma unroll
  for (int k = 0; k < H; k++) acc += smid[k] * tW2[k * H + j];
  table[bidx * H + j] = acc;
}

// ---------------- small fp32 tiled GEMM (K mult of 16, any Nc mult of 4) ----------------
__global__ __launch_bounds__(256) void k_gemm(const float* __restrict__ A, const float* __restrict__ W,
    const float* __restrict__ bias, float* __restrict__ C, int M, int K, int Nc){
  __shared__ float As[16][68];
  __shared__ float Ws[16][64];
  int t = threadIdx.x;
  int m0 = blockIdx.x * 64, n0 = blockIdx.y * 64;
  int tx = t & 15, ty = t >> 4;
  int la_m = t >> 2, la_k = (t & 3) << 2;
  int lw_k = t >> 4, lw_j = (t & 15) << 2;
  float acc[4][4] = {{0.f}};
  int arow = m0 + la_m;
  for (int k0 = 0; k0 < K; k0 += 16){
    float4 a = make_float4(0.f, 0.f, 0.f, 0.f);
    if (arow < M) a = *(const float4*)(A + (size_t)arow * K + k0 + la_k);
    As[la_k + 0][la_m] = a.x; As[la_k + 1][la_m] = a.y;
    As[la_k + 2][la_m] = a.z; As[la_k + 3][la_m] = a.w;
    float4 wv = make_float4(0.f, 0.f, 0.f, 0.f);
    if (n0 + lw_j < Nc) wv = *(const float4*)(W + (size_t)(k0 + lw_k) * Nc + n0 + lw_j);
    *(float4*)&Ws[lw_k][lw_j] = wv;
    __syncthreads();
    #pragma unroll
    for (int k = 0; k < 16; k++){
      float4 a4 = *(const float4*)&As[k][ty << 2];
      float4 b4 = *(const float4*)&Ws[k][tx << 2];
      acc[0][0] += a4.x * b4.x; acc[0][1] += a4.x * b4.y; acc[0][2] += a4.x * b4.z; acc[0][3] += a4.x * b4.w;
      acc[1][0] += a4.y * b4.x; acc[1][1] += a4.y * b4.y; acc[1][2] += a4.y * b4.z; acc[1][3] += a4.y * b4.w;
      acc[2][0] += a4.z * b4.x; acc[2][1] += a4.z * b4.y; acc[2][2] += a4.z * b4.z; acc[2][3] += a4.z * b4.w;
      acc[3][0] += a4.w * b4.x; acc[3][1] += a4.w * b4.y; acc[3][2] += a4.w * b4.z; acc[3][3] += a4.w * b4.w;
    }
    __syncthreads();
  }
  int col = n0 + (tx << 2);
  if (col < Nc){
    float4 b4 = make_float4(0.f, 0.f, 0.f, 0.f);
    if (bias) b4 = *(const float4*)(bias + col);
    #pragma unroll
    for (int r = 0; r < 4; r++){
      int row = m0 + (ty << 2) + r;
      if (row < M){
        float4 o = make_float4(acc[r][0] + b4.x, acc[r][1] + b4.y, acc[r][2] + b4.z, acc[r][3] + b4.w);
        *(float4*)(C + (size_t)row * Nc + col) = o;
      }
    }
  }
}

// ---------------- big fp32 GEMM: 128x128 tile, 8x8 micro, BK=16 ----------------
// K multiple of 16, Nc multiple of 4; A rows 16B-aligned (K mult of 4).
__global__ __launch_bounds__(256) void k_gemm128(const float* __restrict__ A, const float* __restrict__ W,
    const float* __restrict__ bias, float* __restrict__ C, int M, int K, int Nc){
  __shared__ float As[16][132];
  __shared__ float Ws[16][128];
  int t = threadIdx.x;
  int m0 = blockIdx.x * 128, n0 = blockIdx.y * 128;
  int tx = t & 15, ty = t >> 4;
  float acc[8][8];
  #pragma unroll
  for (int r = 0; r < 8; r++)
    #pragma unroll
    for (int c = 0; c < 8; c++) acc[r][c] = 0.f;
  for (int k0 = 0; k0 < K; k0 += 16){
    #pragma unroll
    for (int l = 0; l < 2; l++){
      int idx = t + l * 256;
      int ar = idx >> 2, ac = (idx & 3) << 2;
      float4 a = make_float4(0.f, 0.f, 0.f, 0.f);
      if (m0 + ar < M) a = *(const float4*)(A + (size_t)(m0 + ar) * K + k0 + ac);
      As[ac + 0][ar] = a.x; As[ac + 1][ar] = a.y;
      As[ac + 2][ar] = a.z; As[ac + 3][ar] = a.w;
    }
    #pragma unroll
    for (int l = 0; l < 2; l++){
      int idx = t + l * 256;
      int wr = idx >> 5, wc = (idx & 31) << 2;
      float4 wv = make_float4(0.f, 0.f, 0.f, 0.f);
      if (n0 + wc < Nc) wv = *(const float4*)(W + (size_t)(k0 + wr) * Nc + n0 + wc);
      *(float4*)&Ws[wr][wc] = wv;
    }
    __syncthreads();
    #pragma unroll
    for (int k = 0; k < 16; k++){
      float4 a0 = *(const float4*)&As[k][ty * 8];
      float4 a1 = *(const float4*)&As[k][ty * 8 + 4];
      float4 b0 = *(const float4*)&Ws[k][tx * 8];
      float4 b1 = *(const float4*)&Ws[k][tx * 8 + 4];
      float ar_[8] = {a0.x, a0.y, a0.z, a0.w, a1.x, a1.y, a1.z, a1.w};
      float bc_[8] = {b0.x, b0.y, b0.z, b0.w, b1.x, b1.y, b1.z, b1.w};
      #pragma unroll
      for (int r = 0; r < 8; r++)
        #pragma unroll
        for (int c = 0; c < 8; c++) acc[r][c] += ar_[r] * bc_[c];
    }
    __syncthreads();
  }
  int col = n0 + tx * 8;
  float4 bb0 = make_float4(0.f, 0.f, 0.f, 0.f), bb1 = bb0;
  if (bias && col < Nc){ bb0 = *(const float4*)(bias + col); bb1 = *(const float4*)(bias + col + 4); }
  #pragma unroll
  for (int r = 0; r < 8; r++){
    int row = m0 + ty * 8 + r;
    if (row < M && col < Nc){
      float4 o0 = make_float4(acc[r][0] + bb0.x, acc[r][1] + bb0.y, acc[r][2] + bb0.z, acc[r][3] + bb0.w);
      float4 o1 = make_float4(acc[r][4] + bb1.x, acc[r][5] + bb1.y, acc[r][6] + bb1.z, acc[r][7] + bb1.w);
      *(float4*)(C + (size_t)row * Nc + col) = o0;
      *(float4*)(C + (size_t)row * Nc + col + 4) = o1;
    }
  }
}

// ---------------- weight packing ----------------
__global__ void k_pack0(const float* __restrict__ Wl, const float* __restrict__ Wr,
    float* __restrict__ Whead, float* __restrict__ Wmid, float* __restrict__ Wtail){
  int r = blockIdx.x, c = threadIdx.x;
  float v = (c < H) ? Wl[r * H + c] : Wr[r * H + (c - H)];
  if (r < 32) Whead[r * 256 + c] = v;
  else if (r < 160) Wmid[(r - 32) * 256 + c] = v;
  else Wtail[(r - 160) * 256 + c] = v;
}
__global__ void k_packW(const float* __restrict__ Wl, const float* __restrict__ Wr, float* __restrict__ Wp){
  int r = blockIdx.x, c = threadIdx.x;
  Wp[r * 256 + c] = (c < H) ? Wl[r * H + c] : Wr[r * H + (c - H)];
}
__global__ void k_bias0(const float* __restrict__ bl, const float* __restrict__ br, float* __restrict__ b0){
  int c = threadIdx.x;
  b0[c] = (c < H) ? bl[c] : br[c - H];
}
__global__ void k_cvec(const float* __restrict__ fcpb, const float* __restrict__ Wp,
    const float* __restrict__ bl, const float* __restrict__ br, float* __restrict__ cc){
  int c = threadIdx.x;
  float acc = (c < H) ? bl[c] : br[c - H];
  for (int k = 0; k < 288; k++) acc += fcpb[k] * Wp[k * 256 + c];
  cc[c] = acc;
}

// ---------------- layer 0 xl/xr assembly ----------------
__global__ __launch_bounds__(256) void k_xlr0(const float* __restrict__ x_t, const int* __restrict__ t,
    const int* __restrict__ batch, const float* __restrict__ T0, const float* __restrict__ H0,
    const float* __restrict__ Whead, const float* __restrict__ b0, float* __restrict__ xlr){
  __shared__ float sx[ND];
  __shared__ int sti, sbi;
  int i = blockIdx.x, c = threadIdx.x;
  if (c < ND) sx[c] = x_t[i * ND + c];
  if (c == 0){ sti = t[i]; sbi = batch[i]; }
  __syncthreads();
  float acc = b0[c] + T0[(size_t)sti * 256 + c] + H0[(size_t)sbi * 256 + c];
  #pragma unroll
  for (int k = 0; k < ND; k++) acc += sx[k] * Whead[k * 256 + c];
  xlr[(size_t)i * 256 + c] = acc;
}

// ---------------- edge-attr mean ----------------
__global__ void k_edge_mean(const float* __restrict__ ea, float* __restrict__ sum16){
  __shared__ float ss[16];
  int t = threadIdx.x;
  if (t < 16) ss[t] = 0.f;
  __syncthreads();
  float p[16];
  #pragma unroll
  for (int k = 0; k < 16; k++) p[k] = 0.f;
  for (int r = blockIdx.x * blockDim.x + t; r < NE; r += gridDim.x * blockDim.x){
    const float4* rp = (const float4*)(ea + (size_t)r * 16);
    float4 q0 = rp[0], q1 = rp[1], q2 = rp[2], q3 = rp[3];
    p[0] += q0.x; p[1] += q0.y; p[2] += q0.z; p[3] += q0.w;
    p[4] += q1.x; p[5] += q1.y; p[6] += q1.z; p[7] += q1.w;
    p[8] += q2.x; p[9] += q2.y; p[10] += q2.z; p[11] += q2.w;
    p[12] += q3.x; p[13] += q3.y; p[14] += q3.z; p[15] += q3.w;
  }
  #pragma unroll
  for (int k = 0; k < 16; k++) atomicAdd(&ss[k], p[k]);
  __syncthreads();
  if (t < 16) atomicAdd(&sum16[t], ss[t]);
}
__global__ void k_mean_scale(float* sum16){
  sum16[threadIdx.x] *= (1.f / NE);
}

// ---------------- CSR build ----------------
__global__ void k_deg_init(int* __restrict__ deg){
  int i = blockIdx.x * 256 + threadIdx.x;
  if (i < NN) deg[i] = 1;  // self loop
}
__global__ void k_deg_count(const int* __restrict__ eidx, int* __restrict__ deg){
  int e = blockIdx.x * 256 + threadIdx.x;
  if (e < NE) atomicAdd(&deg[eidx[NE + e]], 1);
}
__global__ __launch_bounds__(256) void k_scan1(const int* __restrict__ deg, int* __restrict__ row_ptr, int* __restrict__ bs){
  __shared__ int sc[256];
  int t = threadIdx.x;
  int base = blockIdx.x * 1024 + t * 4;
  int v0 = (base + 0 < NN) ? deg[base + 0] : 0;
  int v1 = (base + 1 < NN) ? deg[base + 1] : 0;
  int v2 = (base + 2 < NN) ? deg[base + 2] : 0;
  int v3 = (base + 3 < NN) ? deg[base + 3] : 0;
  int s0 = v0, s1 = s0 + v1, s2 = s1 + v2, s3 = s2 + v3;
  sc[t] = s3;
  __syncthreads();
  for (int off = 1; off < 256; off <<= 1){
    int add = (t >= off) ? sc[t - off] : 0;
    __syncthreads();
    sc[t] += add;
    __syncthreads();
  }
  int excl = sc[t] - s3;
  if (base + 0 < NN) row_ptr[base + 1] = excl + s0;
  if (base + 1 < NN) row_ptr[base + 2] = excl + s1;
  if (base + 2 < NN) row_ptr[base + 3] = excl + s2;
  if (base + 3 < NN) row_ptr[base + 4] = excl + s3;
  if (t == 255) bs[blockIdx.x] = sc[255];
}
__global__ void k_scan2(int* __restrict__ bs, int nb){
  int lane = threadIdx.x;
  int v = (lane < nb) ? bs[lane] : 0;
  for (int off = 1; off < 64; off <<= 1){
    int n = __shfl_up(v, off, 64);
    if (lane >= off) v += n;
  }
  if (lane < nb) bs[lane] = v;
}
__global__ void k_scan3(int* __restrict__ row_ptr, const int* __restrict__ bs){
  int i = blockIdx.x * 256 + threadIdx.x;
  if (i == 0) row_ptr[0] = 0;
  if (i < NN){
    int chunk = i >> 10;
    if (chunk > 0) row_ptr[i + 1] += bs[chunk - 1];
  }
}
__global__ void k_fill_init(const int* __restrict__ row_ptr, int* __restrict__ fill){
  int i = blockIdx.x * 256 + threadIdx.x;
  if (i < NN) fill[i] = row_ptr[i];
}
__global__ void k_fill_edges(const int* __restrict__ eidx, int* __restrict__ fill,
    int* __restrict__ csrc, int* __restrict__ ceid){
  int e = blockIdx.x * 256 + threadIdx.x;
  if (e < NE){
    int d = eidx[NE + e];
    int pos = atomicAdd(&fill[d], 1);
    csrc[pos] = eidx[e];
    ceid[pos] = e;
  }
}
__global__ void k_fill_self(int* __restrict__ fill, int* __restrict__ csrc, int* __restrict__ ceid){
  int i = blockIdx.x * 256 + threadIdx.x;
  if (i < NN){
    int pos = atomicAdd(&fill[i], 1);
    csrc[pos] = i;
    ceid[pos] = NE;  // sentinel: mean edge-attr row
  }
}

// ---------------- fused GATv2 score + softmax aggregation + silu ----------------
// wave per node, 2 dims/lane, online softmax, software-pipelined edge loop.
__global__ __launch_bounds__(256) void k_sagg(const float* __restrict__ xlr,
    const float* __restrict__ ea, const float* __restrict__ eamean,
    const float* __restrict__ Wel, const float* __restrict__ attl, const float* __restrict__ gbl,
    const int* __restrict__ row_ptr, const int* __restrict__ csrc, const int* __restrict__ ceid,
    float* __restrict__ y){
  int t = threadIdx.x;
  int wid = t >> 6, lane = t & 63;
  int i = blockIdx.x * 4 + wid;
  if (i >= NN) return;
  int dim = lane << 1;
  float2 rW[16];
  #pragma unroll
  for (int k = 0; k < 16; k++) rW[k] = *(const float2*)(Wel + k * H + dim);
  float2 xr = *(const float2*)(xlr + (size_t)i * 256 + H + dim);
  float a0 = attl[dim], a1 = attl[dim + 1];
  int row = __builtin_amdgcn_readfirstlane(row_ptr[i]);
  int end = __builtin_amdgcn_readfirstlane(row_ptr[i + 1]);
  float m = -1e30f, den = 0.f, ax = 0.f, ay = 0.f;
  // prefetch edge `row`
  int s_c = __builtin_amdgcn_readfirstlane(csrc[row]);
  int e_c = __builtin_amdgcn_readfirstlane(ceid[row]);
  float2 vl_c = *(const float2*)(xlr + (size_t)s_c * 256 + dim);
  const float* ep_c = (e_c < NE) ? (ea + (size_t)e_c * 16) : eamean;
  float4 q0 = *(const float4*)(ep_c);
  float4 q1 = *(const float4*)(ep_c + 4);
  float4 q2 = *(const float4*)(ep_c + 8);
  float4 q3 = *(const float4*)(ep_c + 12);
  for (int p = row; p < end; ++p){
    // issue next edge's loads (clamped; redundant on last iter)
    int pn = (p + 1 < end) ? (p + 1) : p;
    int s_n = __builtin_amdgcn_readfirstlane(csrc[pn]);
    int e_n = __builtin_amdgcn_readfirstlane(ceid[pn]);
    float2 vl_n = *(const float2*)(xlr + (size_t)s_n * 256 + dim);
    const float* ep_n = (e_n < NE) ? (ea + (size_t)e_n * 16) : eamean;
    float4 n0 = *(const float4*)(ep_n);
    float4 n1 = *(const float4*)(ep_n + 4);
    float4 n2 = *(const float4*)(ep_n + 8);
    float4 n3 = *(const float4*)(ep_n + 12);
    // compute current edge
    float eav[16] = {q0.x, q0.y, q0.z, q0.w, q1.x, q1.y, q1.z, q1.w,
                     q2.x, q2.y, q2.z, q2.w, q3.x, q3.y, q3.z, q3.w};
    float ew0 = 0.f, ew1 = 0.f;
    #pragma unroll
    for (int k = 0; k < 16; k++){ ew0 += eav[k] * rW[k].x; ew1 += eav[k] * rW[k].y; }
    float vx = vl_c.x + xr.x + ew0;
    float vy = vl_c.y + xr.y + ew1;
    vx = fmaxf(vx, NEG * vx);
    vy = fmaxf(vy, NEG * vy);
    float sc = wsum(a0 * vx + a1 * vy);
    if (sc <= m){                      // wave-uniform: no rescale needed (scale==1)
      float wv = __expf(sc - m);
      den += wv; ax += wv * vl_c.x; ay += wv * vl_c.y;
    } else {                           // new max: wv = exp(0) = 1
      float scale = __expf(m - sc);
      den = den * scale + 1.f;
      ax = ax * scale + vl_c.x;
      ay = ay * scale + vl_c.y;
      m = sc;
    }
    // rotate pipeline
    vl_c = vl_n; q0 = n0; q1 = n1; q2 = n2; q3 = n3;
  }
  float inv = 1.f / (den + 1e-16f);
  float ox = siluf(ax * inv + gbl[dim]);
  float oy = siluf(ay * inv + gbl[dim + 1]);
  *(float2*)(y + (size_t)i * H + dim) = make_float2(ox, oy);
}

// ---------------- LayerNorm + SiLU row kernel ----------------
__global__ __launch_bounds__(128) void k_ln_silu(const float* __restrict__ z, const float* __restrict__ g,
    const float* __restrict__ b, float* __restrict__ z2){
  __shared__ float red[4];
  int i = blockIdx.x, j = threadIdx.x;
  float x = z[(size_t)i * H + j];
  float v = blockLN128(x, g, b, j, red);
  z2[(size_t)i * H + j] = siluf(v);
}

extern "C" void kernel_launch(void* const* d_in, const int* in_sizes, int n_in,
                              void* d_out, int out_size, void* d_ws, size_t ws_size,
                              hipStream_t stream){
  (void)in_sizes; (void)n_in; (void)out_size; (void)ws_size;
  const float* x_t  = (const float*)d_in[0];
  const int*   t    = (const int*)d_in[1];
  const float* hf   = (const float*)d_in[2];
  const int*   eidx = (const int*)d_in[3];
  const float* ea   = (const float*)d_in[4];
  const int*   batch= (const int*)d_in[5];
  const float* tW1  = (const float*)d_in[6];
  const float* tb1  = (const float*)d_in[7];
  const float* tW2  = (const float*)d_in[8];
  const float* tb2  = (const float*)d_in[9];
  const float* hW1  = (const float*)d_in[10];
  const float* hb1  = (const float*)d_in[11];
  const float* hg1  = (const float*)d_in[12];
  const float* hB1  = (const float*)d_in[13];
  const float* hW2  = (const float*)d_in[14];
  const float* hb2  = (const float*)d_in[15];
  const float* hg2  = (const float*)d_in[16];
  const float* hB2  = (const float*)d_in[17];
  const float* Wl   = (const float*)d_in[18];
  const float* bl   = (const float*)d_in[19];
  const float* Wr   = (const float*)d_in[20];
  const float* br   = (const float*)d_in[21];
  const float* We   = (const float*)d_in[22];
  const float* att  = (const float*)d_in[23];
  const float* gb   = (const float*)d_in[24];
  const float* fcpW = (const float*)d_in[25];
  const float* fcpb = (const float*)d_in[26];
  const float* npW1 = (const float*)d_in[27];
  const float* npb1 = (const float*)d_in[28];
  const float* npg  = (const float*)d_in[29];
  const float* npB  = (const float*)d_in[30];
  const float* npW2 = (const float*)d_in[31];
  const float* npb2 = (const float*)d_in[32];

  char* w = (char*)d_ws;
  size_t off = 0;
  auto alloc = [&](size_t bytes) -> void* {
    void* p = w + off;
    off += (bytes + 255) & ~(size_t)255;
    return p;
  };
  float* table = (float*)alloc((size_t)1000 * H * 4);
  float* hbuf  = (float*)alloc((size_t)NB * H * 4);
  float* T0    = (float*)alloc((size_t)1000 * 256 * 4);
  float* H0b   = (float*)alloc((size_t)NB * 256 * 4);
  float* W0h   = (float*)alloc((size_t)32 * 256 * 4);
  float* W0m   = (float*)alloc((size_t)128 * 256 * 4);
  float* W0t   = (float*)alloc((size_t)128 * 256 * 4);
  float* b0    = (float*)alloc(256 * 4);
  float* Wp1   = (float*)alloc((size_t)288 * 256 * 4);
  float* Wp2   = (float*)alloc((size_t)288 * 256 * 4);
  float* Ac1   = (float*)alloc((size_t)128 * 256 * 4);
  float* Ac2   = (float*)alloc((size_t)128 * 256 * 4);
  float* cc1   = (float*)alloc(256 * 4);
  float* cc2   = (float*)alloc(256 * 4);
  float* eam   = (float*)alloc(16 * 4);
  int* deg     = (int*)alloc((size_t)NN * 4);
  int* row_ptr = (int*)alloc((size_t)(NN + 1) * 4);
  int* fill    = (int*)alloc((size_t)NN * 4);
  int* bs      = (int*)alloc(64 * 4);
  int* csrc    = (int*)alloc((size_t)ETOT * 4);
  int* ceid    = (int*)alloc((size_t)ETOT * 4);
  float* xlr   = (float*)alloc((size_t)NN * 256 * 4);
  float* y     = (float*)alloc((size_t)NN * H * 4);
  float* z  = xlr;                      // reuse (free at nodeproj time)
  float* z2 = xlr + (size_t)NN * H;

  hipMemsetAsync(eam, 0, 64, stream);
  k_edge_mean<<<512, 256, 0, stream>>>(ea, eam);
  k_mean_scale<<<1, 16, 0, stream>>>(eam);
  k_house<<<NB, 128, 0, stream>>>(hf, hW1, hb1, hg1, hB1, hW2, hb2, hg2, hB2, hbuf);
  k_temb<<<1000, 128, 0, stream>>>(tW1, tb1, tW2, tb2, table);
  // CSR build
  k_deg_init<<<(NN + 255) / 256, 256, 0, stream>>>(deg);
  k_deg_count<<<(NE + 255) / 256, 256, 0, stream>>>(eidx, deg);
  k_scan1<<<49, 256, 0, stream>>>(deg, row_ptr, bs);
  k_scan2<<<1, 64, 0, stream>>>(bs, 49);
  k_scan3<<<(NN + 255) / 256, 256, 0, stream>>>(row_ptr, bs);
  k_fill_init<<<(NN + 255) / 256, 256, 0, stream>>>(row_ptr, fill);
  k_fill_edges<<<(NE + 255) / 256, 256, 0, stream>>>(eidx, fill, csrc, ceid);
  k_fill_self<<<(NN + 255) / 256, 256, 0, stream>>>(fill, csrc, ceid);
  // weight packing + folded precomputes
  k_pack0<<<288, 256, 0, stream>>>(Wl, Wr, W0h, W0m, W0t);
  k_bias0<<<1, 256, 0, stream>>>(bl, br, b0);
  k_packW<<<288, 256, 0, stream>>>(Wl + 1 * 288 * H, Wr + 1 * 288 * H, Wp1);
  k_packW<<<288, 256, 0, stream>>>(Wl + 2 * 288 * H, Wr + 2 * 288 * H, Wp2);
  k_cvec<<<1, 256, 0, stream>>>(fcpb, Wp1, bl + H, br + H, cc1);
  k_cvec<<<1, 256, 0, stream>>>(fcpb, Wp2, bl + 2 * H, br + 2 * H, cc2);
  auto gemm = [&](const float* A, const float* W_, const float* bias, float* C, int M, int K, int Nc){
    dim3 g((M + 63) / 64, (Nc + 63) / 64);
    k_gemm<<<g, 256, 0, stream>>>(A, W_, bias, C, M, K, Nc);
  };
  auto gemm128 = [&](const float* A, const float* W_, const float* bias, float* C, int M, int K, int Nc){
    dim3 g((M + 127) / 128, (Nc + 127) / 128);
    k_gemm128<<<g, 256, 0, stream>>>(A, W_, bias, C, M, K, Nc);
  };
  gemm128(table, W0m, nullptr, T0, 1000, H, 256);
  gemm128(hbuf, W0t, nullptr, H0b, NB, H, 256);
  gemm(fcpW, Wp1, nullptr, Ac1, H, 288, 256);
  gemm(fcpW, Wp2, nullptr, Ac2, H, 288, 256);
  // ---- layer 0 ----
  k_xlr0<<<NN, 256, 0, stream>>>(x_t, t, batch, T0, H0b, W0h, b0, xlr);
  k_sagg<<<(NN + 3) / 4, 256, 0, stream>>>(xlr, ea, eam, We, att, gb, row_ptr, csrc, ceid, y);
  // ---- layer 1 (fc_projection folded into A,c) ----
  gemm128(y, Ac1, cc1, xlr, NN, H, 256);
  k_sagg<<<(NN + 3) / 4, 256, 0, stream>>>(xlr, ea, eam, We + 16 * H, att + H, gb + H, row_ptr, csrc, ceid, y);
  // ---- layer 2 ----
  gemm128(y, Ac2, cc2, xlr, NN, H, 256);
  k_sagg<<<(NN + 3) / 4, 256, 0, stream>>>(xlr, ea, eam, We + 32 * H, att + 2 * H, gb + 2 * H, row_ptr, csrc, ceid, y);
  // ---- node projection ----
  gemm128(y, npW1, npb1, z, NN, H, H);
  k_ln_silu<<<NN, 128, 0, stream>>>(z, npg, npB, z2);
  gemm(z2, npW2, npb2, (float*)d_out, NN, H, ND);
}

// Round 4
// 959.125 us; speedup vs baseline: 1.1041x; 1.1041x over previous
//
#include <hip/hip_runtime.h>
#include <hip/hip_bf16.h>

#define NN 50000
#define NE 800000
#define NB 5000
#define ND 32
#define EDD 16
#define HDD 64
#define H 128
#define ETOT (NE + NN)
#define NEG 0.2f
#define EPS_LN 1e-5f

typedef float pf2 __attribute__((ext_vector_type(2)));

__device__ __forceinline__ float siluf(float x){ return x / (1.f + __expf(-x)); }

__device__ __forceinline__ float wsum(float v){
  v += __shfl_xor(v, 32, 64);
  v += __shfl_xor(v, 16, 64);
  v += __shfl_xor(v, 8, 64);
  v += __shfl_xor(v, 4, 64);
  v += __shfl_xor(v, 2, 64);
  v += __shfl_xor(v, 1, 64);
  return v;
}

// DPP-based full-wave sum, result uniform (classic row_shr + bcast chain, readlane 63)
#define DPP_ADD(v, ctrl) \
  v += __builtin_bit_cast(float, __builtin_amdgcn_update_dpp(0, __builtin_bit_cast(int, v), ctrl, 0xf, 0xf, true))
__device__ __forceinline__ float wsum_bcast(float v){
  DPP_ADD(v, 0x111);  // row_shr:1
  DPP_ADD(v, 0x112);  // row_shr:2
  DPP_ADD(v, 0x114);  // row_shr:4
  DPP_ADD(v, 0x118);  // row_shr:8
  DPP_ADD(v, 0x142);  // row_bcast:15
  DPP_ADD(v, 0x143);  // row_bcast:31
  return __builtin_bit_cast(float, __builtin_amdgcn_readlane(__builtin_bit_cast(int, v), 63));
}

// LayerNorm across a 128-thread block (one row), j = threadIdx.x
__device__ __forceinline__ float blockLN128(float x, const float* g, const float* b, int j, float* red){
  int lane = j & 63, wid = j >> 6;
  float s = wsum(x);
  if (lane == 0) red[wid] = s;
  __syncthreads();
  float mu = (red[0] + red[1]) * 0.0078125f;
  float d = x - mu;
  float s2 = wsum(d * d);
  if (lane == 0) red[2 + wid] = s2;
  __syncthreads();
  float var = (red[2] + red[3]) * 0.0078125f;
  return d * (1.f / sqrtf(var + EPS_LN)) * g[j] + b[j];
}

// ---------------- household encoder ----------------
__global__ __launch_bounds__(128) void k_house(const float* __restrict__ hf,
    const float* __restrict__ hW1, const float* __restrict__ hb1,
    const float* __restrict__ hg1, const float* __restrict__ hB1,
    const float* __restrict__ hW2, const float* __restrict__ hb2,
    const float* __restrict__ hg2, const float* __restrict__ hB2,
    float* __restrict__ hout){
  __shared__ float sin_[HDD];
  __shared__ float smid[H];
  __shared__ float red[4];
  int bidx = blockIdx.x, j = threadIdx.x;
  if (j < HDD) sin_[j] = hf[bidx * HDD + j];
  __syncthreads();
  float acc = hb1[j];
  #pragma unroll
  for (int k = 0; k < HDD; k++) acc += sin_[k] * hW1[k * H + j];
  float v = siluf(blockLN128(acc, hg1, hB1, j, red));
  __syncthreads();
  smid[j] = v;
  __syncthreads();
  float acc2 = hb2[j];
  #pragma unroll
  for (int k = 0; k < H; k++) acc2 += smid[k] * hW2[k * H + j];
  float v2 = siluf(blockLN128(acc2, hg2, hB2, j, red));
  hout[bidx * H + j] = v2;
}

// ---------------- time embedding table ----------------
__global__ __launch_bounds__(128) void k_temb(const float* __restrict__ tW1, const float* __restrict__ tb1,
    const float* __restrict__ tW2, const float* __restrict__ tb2, float* __restrict__ table){
  __shared__ float smid[H];
  int bidx = blockIdx.x, j = threadIdx.x;
  float tv = (float)bidx;
  smid[j] = siluf(tv * tW1[j] + tb1[j]);
  __syncthreads();
  float acc = tb2[j];
  #pragma unroll
  for (int k = 0; k < H; k++) acc += smid[k] * tW2[k * H + j];
  table[bidx * H + j] = acc;
}

// ---------------- small fp32 tiled GEMM (64x64 tile) ----------------
__global__ __launch_bounds__(256) void k_gemm(const float* __restrict__ A, const float* __restrict__ W,
    const float* __restrict__ bias, float* __restrict__ C, int M, int K, int Nc){
  __shared__ float As[16][68];
  __shared__ float Ws[16][64];
  int t = threadIdx.x;
  int m0 = blockIdx.x * 64, n0 = blockIdx.y * 64;
  int tx = t & 15, ty = t >> 4;
  int la_m = t >> 2, la_k = (t & 3) << 2;
  int lw_k = t >> 4, lw_j = (t & 15) << 2;
  float acc[4][4] = {{0.f}};
  int arow = m0 + la_m;
  for (int k0 = 0; k0 < K; k0 += 16){
    float4 a = make_float4(0.f, 0.f, 0.f, 0.f);
    if (arow < M) a = *(const float4*)(A + (size_t)arow * K + k0 + la_k);
    As[la_k + 0][la_m] = a.x; As[la_k + 1][la_m] = a.y;
    As[la_k + 2][la_m] = a.z; As[la_k + 3][la_m] = a.w;
    float4 wv = make_float4(0.f, 0.f, 0.f, 0.f);
    if (n0 + lw_j < Nc) wv = *(const float4*)(W + (size_t)(k0 + lw_k) * Nc + n0 + lw_j);
    *(float4*)&Ws[lw_k][lw_j] = wv;
    __syncthreads();
    #pragma unroll
    for (int k = 0; k < 16; k++){
      float4 a4 = *(const float4*)&As[k][ty << 2];
      float4 b4 = *(const float4*)&Ws[k][tx << 2];
      acc[0][0] += a4.x * b4.x; acc[0][1] += a4.x * b4.y; acc[0][2] += a4.x * b4.z; acc[0][3] += a4.x * b4.w;
      acc[1][0] += a4.y * b4.x; acc[1][1] += a4.y * b4.y; acc[1][2] += a4.y * b4.z; acc[1][3] += a4.y * b4.w;
      acc[2][0] += a4.z * b4.x; acc[2][1] += a4.z * b4.y; acc[2][2] += a4.z * b4.z; acc[2][3] += a4.z * b4.w;
      acc[3][0] += a4.w * b4.x; acc[3][1] += a4.w * b4.y; acc[3][2] += a4.w * b4.z; acc[3][3] += a4.w * b4.w;
    }
    __syncthreads();
  }
  int col = n0 + (tx << 2);
  if (col < Nc){
    float4 b4 = make_float4(0.f, 0.f, 0.f, 0.f);
    if (bias) b4 = *(const float4*)(bias + col);
    #pragma unroll
    for (int r = 0; r < 4; r++){
      int row = m0 + (ty << 2) + r;
      if (row < M){
        float4 o = make_float4(acc[r][0] + b4.x, acc[r][1] + b4.y, acc[r][2] + b4.z, acc[r][3] + b4.w);
        *(float4*)(C + (size_t)row * Nc + col) = o;
      }
    }
  }
}

// ---------------- big fp32 GEMM: 128x128 tile, 8x8 micro, BK=16 ----------------
__global__ __launch_bounds__(256) void k_gemm128(const float* __restrict__ A, const float* __restrict__ W,
    const float* __restrict__ bias, float* __restrict__ C, int M, int K, int Nc){
  __shared__ float As[16][132];
  __shared__ float Ws[16][128];
  int t = threadIdx.x;
  int m0 = blockIdx.x * 128, n0 = blockIdx.y * 128;
  int tx = t & 15, ty = t >> 4;
  float acc[8][8];
  #pragma unroll
  for (int r = 0; r < 8; r++)
    #pragma unroll
    for (int c = 0; c < 8; c++) acc[r][c] = 0.f;
  for (int k0 = 0; k0 < K; k0 += 16){
    #pragma unroll
    for (int l = 0; l < 2; l++){
      int idx = t + l * 256;
      int ar = idx >> 2, ac = (idx & 3) << 2;
      float4 a = make_float4(0.f, 0.f, 0.f, 0.f);
      if (m0 + ar < M) a = *(const float4*)(A + (size_t)(m0 + ar) * K + k0 + ac);
      As[ac + 0][ar] = a.x; As[ac + 1][ar] = a.y;
      As[ac + 2][ar] = a.z; As[ac + 3][ar] = a.w;
    }
    #pragma unroll
    for (int l = 0; l < 2; l++){
      int idx = t + l * 256;
      int wr = idx >> 5, wc = (idx & 31) << 2;
      float4 wv = make_float4(0.f, 0.f, 0.f, 0.f);
      if (n0 + wc < Nc) wv = *(const float4*)(W + (size_t)(k0 + wr) * Nc + n0 + wc);
      *(float4*)&Ws[wr][wc] = wv;
    }
    __syncthreads();
    #pragma unroll
    for (int k = 0; k < 16; k++){
      float4 a0 = *(const float4*)&As[k][ty * 8];
      float4 a1 = *(const float4*)&As[k][ty * 8 + 4];
      float4 b0 = *(const float4*)&Ws[k][tx * 8];
      float4 b1 = *(const float4*)&Ws[k][tx * 8 + 4];
      float ar_[8] = {a0.x, a0.y, a0.z, a0.w, a1.x, a1.y, a1.z, a1.w};
      float bc_[8] = {b0.x, b0.y, b0.z, b0.w, b1.x, b1.y, b1.z, b1.w};
      #pragma unroll
      for (int r = 0; r < 8; r++)
        #pragma unroll
        for (int c = 0; c < 8; c++) acc[r][c] += ar_[r] * bc_[c];
    }
    __syncthreads();
  }
  int col = n0 + tx * 8;
  float4 bb0 = make_float4(0.f, 0.f, 0.f, 0.f), bb1 = bb0;
  if (bias && col < Nc){ bb0 = *(const float4*)(bias + col); bb1 = *(const float4*)(bias + col + 4); }
  #pragma unroll
  for (int r = 0; r < 8; r++){
    int row = m0 + ty * 8 + r;
    if (row < M && col < Nc){
      float4 o0 = make_float4(acc[r][0] + bb0.x, acc[r][1] + bb0.y, acc[r][2] + bb0.z, acc[r][3] + bb0.w);
      float4 o1 = make_float4(acc[r][4] + bb1.x, acc[r][5] + bb1.y, acc[r][6] + bb1.z, acc[r][7] + bb1.w);
      *(float4*)(C + (size_t)row * Nc + col) = o0;
      *(float4*)(C + (size_t)row * Nc + col + 4) = o1;
    }
  }
}

// ---------------- GEMM (M x 128 x 128) fused with LayerNorm + SiLU epilogue ----------------
__global__ __launch_bounds__(256) void k_gemmln(const float* __restrict__ A, const float* __restrict__ W,
    const float* __restrict__ bias, const float* __restrict__ g, const float* __restrict__ B,
    float* __restrict__ out, int M){
  __shared__ float As[16][132];
  __shared__ float Ws[16][128];
  int t = threadIdx.x;
  int m0 = blockIdx.x * 128;
  int tx = t & 15, ty = t >> 4;
  float acc[8][8];
  #pragma unroll
  for (int r = 0; r < 8; r++)
    #pragma unroll
    for (int c = 0; c < 8; c++) acc[r][c] = 0.f;
  for (int k0 = 0; k0 < H; k0 += 16){
    #pragma unroll
    for (int l = 0; l < 2; l++){
      int idx = t + l * 256;
      int ar = idx >> 2, ac = (idx & 3) << 2;
      float4 a = make_float4(0.f, 0.f, 0.f, 0.f);
      if (m0 + ar < M) a = *(const float4*)(A + (size_t)(m0 + ar) * H + k0 + ac);
      As[ac + 0][ar] = a.x; As[ac + 1][ar] = a.y;
      As[ac + 2][ar] = a.z; As[ac + 3][ar] = a.w;
    }
    #pragma unroll
    for (int l = 0; l < 2; l++){
      int idx = t + l * 256;
      int wr = idx >> 5, wc = (idx & 31) << 2;
      *(float4*)&Ws[wr][wc] = *(const float4*)(W + (size_t)(k0 + wr) * H + wc);
    }
    __syncthreads();
    #pragma unroll
    for (int k = 0; k < 16; k++){
      float4 a0 = *(const float4*)&As[k][ty * 8];
      float4 a1 = *(const float4*)&As[k][ty * 8 + 4];
      float4 b0 = *(const float4*)&Ws[k][tx * 8];
      float4 b1 = *(const float4*)&Ws[k][tx * 8 + 4];
      float ar_[8] = {a0.x, a0.y, a0.z, a0.w, a1.x, a1.y, a1.z, a1.w};
      float bc_[8] = {b0.x, b0.y, b0.z, b0.w, b1.x, b1.y, b1.z, b1.w};
      #pragma unroll
      for (int r = 0; r < 8; r++)
        #pragma unroll
        for (int c = 0; c < 8; c++) acc[r][c] += ar_[r] * bc_[c];
    }
    __syncthreads();
  }
  int col = tx * 8;
  float bb[8], gv[8], Bv[8];
  *(float4*)&bb[0] = *(const float4*)(bias + col); *(float4*)&bb[4] = *(const float4*)(bias + col + 4);
  *(float4*)&gv[0] = *(const float4*)(g + col);    *(float4*)&gv[4] = *(const float4*)(g + col + 4);
  *(float4*)&Bv[0] = *(const float4*)(B + col);    *(float4*)&Bv[4] = *(const float4*)(B + col + 4);
  #pragma unroll
  for (int r = 0; r < 8; r++){
    int row = m0 + ty * 8 + r;
    if (row >= M) continue;   // uniform across the 16-lane shfl group (row depends on ty,r only)
    float v[8];
    float s = 0.f;
    #pragma unroll
    for (int c = 0; c < 8; c++){ v[c] = acc[r][c] + bb[c]; s += v[c]; }
    s += __shfl_xor(s, 1, 16); s += __shfl_xor(s, 2, 16);
    s += __shfl_xor(s, 4, 16); s += __shfl_xor(s, 8, 16);
    float mu = s * 0.0078125f;
    float s2 = 0.f;
    #pragma unroll
    for (int c = 0; c < 8; c++){ v[c] -= mu; s2 += v[c] * v[c]; }
    s2 += __shfl_xor(s2, 1, 16); s2 += __shfl_xor(s2, 2, 16);
    s2 += __shfl_xor(s2, 4, 16); s2 += __shfl_xor(s2, 8, 16);
    float rstd = 1.f / sqrtf(s2 * 0.0078125f + EPS_LN);
    float o[8];
    #pragma unroll
    for (int c = 0; c < 8; c++) o[c] = siluf(v[c] * rstd * gv[c] + Bv[c]);
    *(float4*)(out + (size_t)row * H + col) = *(float4*)&o[0];
    *(float4*)(out + (size_t)row * H + col + 4) = *(float4*)&o[4];
  }
}

// ---------------- weight packing (all three layers in one launch) ----------------
__global__ void k_packs(const float* __restrict__ Wl, const float* __restrict__ Wr,
    float* __restrict__ W0h, float* __restrict__ W0m, float* __restrict__ W0t,
    float* __restrict__ Wp1, float* __restrict__ Wp2){
  int r = blockIdx.x, L = blockIdx.y, c = threadIdx.x;
  float v = (c < H) ? Wl[(size_t)L * 288 * H + r * H + c] : Wr[(size_t)L * 288 * H + r * H + (c - H)];
  if (L == 0){
    if (r < 32) W0h[r * 256 + c] = v;
    else if (r < 160) W0m[(r - 32) * 256 + c] = v;
    else W0t[(r - 160) * 256 + c] = v;
  } else {
    (L == 1 ? Wp1 : Wp2)[r * 256 + c] = v;
  }
}
// b0 assembly + eam scaling + folded cc vectors (reads Wl/Wr directly)
__global__ void k_small(const float* __restrict__ bl, const float* __restrict__ br,
    const float* __restrict__ Wl, const float* __restrict__ Wr, const float* __restrict__ fcpb,
    float* __restrict__ b0, float* __restrict__ cc1, float* __restrict__ cc2, float* __restrict__ eam){
  int c = threadIdx.x, which = blockIdx.x;
  if (which == 0){
    b0[c] = (c < H) ? bl[c] : br[c - H];
    if (c < 16) eam[c] *= (1.f / NE);
  } else {
    int cc = (c < H) ? c : c - H;
    const float* Wsrc = ((c < H) ? Wl : Wr) + (size_t)which * 288 * H;
    float acc = (c < H) ? bl[which * H + cc] : br[which * H + cc];
    for (int k = 0; k < 288; k++) acc += fcpb[k] * Wsrc[k * H + cc];
    (which == 1 ? cc1 : cc2)[c] = acc;
  }
}

// ---------------- layer 0 xl/xr assembly: 4 nodes/block, float4 per lane ----------------
__global__ __launch_bounds__(256) void k_xlr0(const float* __restrict__ x_t, const int* __restrict__ tt,
    const int* __restrict__ batch, const float* __restrict__ T0, const float* __restrict__ H0,
    const float* __restrict__ Whead, const float* __restrict__ b0, float* __restrict__ xlr){
  __shared__ float sx[4][ND];
  __shared__ int sti[4], sbi[4];
  int b4 = blockIdx.x * 4;
  int t = threadIdx.x;
  if (t < 128){
    int n = t >> 5, k = t & 31;
    int i = b4 + n;
    if (i < NN) sx[n][k] = x_t[(size_t)i * ND + k];
  }
  if (t < 4){
    int i = b4 + t;
    if (i < NN){ sti[t] = tt[i]; sbi[t] = batch[i]; }
  }
  __syncthreads();
  int wid = t >> 6, lane = t & 63;
  int i = b4 + wid;
  if (i >= NN) return;
  int c = lane << 2;
  float4 acc = *(const float4*)(b0 + c);
  float4 tv = *(const float4*)(T0 + (size_t)sti[wid] * 256 + c);
  float4 hv = *(const float4*)(H0 + (size_t)sbi[wid] * 256 + c);
  acc.x += tv.x + hv.x; acc.y += tv.y + hv.y; acc.z += tv.z + hv.z; acc.w += tv.w + hv.w;
  #pragma unroll
  for (int k = 0; k < ND; k++){
    float xk = sx[wid][k];
    float4 wv = *(const float4*)(Whead + k * 256 + c);
    acc.x += xk * wv.x; acc.y += xk * wv.y; acc.z += xk * wv.z; acc.w += xk * wv.w;
  }
  *(float4*)(xlr + (size_t)i * 256 + c) = acc;
}

// ---------------- edge-attr mean ----------------
__global__ void k_edge_mean(const float* __restrict__ ea, float* __restrict__ sum16){
  __shared__ float ss[16];
  int t = threadIdx.x;
  if (t < 16) ss[t] = 0.f;
  __syncthreads();
  float p[16];
  #pragma unroll
  for (int k = 0; k < 16; k++) p[k] = 0.f;
  for (int r = blockIdx.x * blockDim.x + t; r < NE; r += gridDim.x * blockDim.x){
    const float4* rp = (const float4*)(ea + (size_t)r * 16);
    float4 q0 = rp[0], q1 = rp[1], q2 = rp[2], q3 = rp[3];
    p[0] += q0.x; p[1] += q0.y; p[2] += q0.z; p[3] += q0.w;
    p[4] += q1.x; p[5] += q1.y; p[6] += q1.z; p[7] += q1.w;
    p[8] += q2.x; p[9] += q2.y; p[10] += q2.z; p[11] += q2.w;
    p[12] += q3.x; p[13] += q3.y; p[14] += q3.z; p[15] += q3.w;
  }
  #pragma unroll
  for (int k = 0; k < 16; k++) atomicAdd(&ss[k], p[k]);
  __syncthreads();
  if (t < 16) atomicAdd(&sum16[t], ss[t]);
}

// ---------------- CSR build ----------------
__global__ void k_deg_count(const int* __restrict__ eidx, int* __restrict__ deg){
  int e = blockIdx.x * 256 + threadIdx.x;
  if (e < NE) atomicAdd(&deg[eidx[NE + e]], 1);
}
__global__ __launch_bounds__(256) void k_scan1(const int* __restrict__ deg, int* __restrict__ row_ptr, int* __restrict__ bs){
  __shared__ int sc[256];
  int t = threadIdx.x;
  int base = blockIdx.x * 1024 + t * 4;
  int v0 = (base + 0 < NN) ? deg[base + 0] + 1 : 0;   // +1 self loop
  int v1 = (base + 1 < NN) ? deg[base + 1] + 1 : 0;
  int v2 = (base + 2 < NN) ? deg[base + 2] + 1 : 0;
  int v3 = (base + 3 < NN) ? deg[base + 3] + 1 : 0;
  int s0 = v0, s1 = s0 + v1, s2 = s1 + v2, s3 = s2 + v3;
  sc[t] = s3;
  __syncthreads();
  for (int off = 1; off < 256; off <<= 1){
    int add = (t >= off) ? sc[t - off] : 0;
    __syncthreads();
    sc[t] += add;
    __syncthreads();
  }
  int excl = sc[t] - s3;
  if (base + 0 < NN) row_ptr[base + 1] = excl + s0;
  if (base + 1 < NN) row_ptr[base + 2] = excl + s1;
  if (base + 2 < NN) row_ptr[base + 3] = excl + s2;
  if (base + 3 < NN) row_ptr[base + 4] = excl + s3;
  if (t == 255) bs[blockIdx.x] = sc[255];
}
__global__ void k_scan2(int* __restrict__ bs, int nb){
  int lane = threadIdx.x;
  int v = (lane < nb) ? bs[lane] : 0;
  for (int off = 1; off < 64; off <<= 1){
    int n = __shfl_up(v, off, 64);
    if (lane >= off) v += n;
  }
  if (lane < nb) bs[lane] = v;
}
__global__ void k_scan3(int* __restrict__ row_ptr, const int* __restrict__ bs,
    const int* __restrict__ deg, int* __restrict__ fill){
  int i = blockIdx.x * 256 + threadIdx.x;
  if (i == 0) row_ptr[0] = 0;
  if (i < NN){
    int chunk = i >> 10;
    int rp1 = row_ptr[i + 1] + ((chunk > 0) ? bs[chunk - 1] : 0);
    row_ptr[i + 1] = rp1;
    fill[i] = rp1 - deg[i] - 1;   // = row_ptr[i]
  }
}
__global__ void k_fill_edges(const int* __restrict__ eidx, int* __restrict__ fill,
    int* __restrict__ csrc, int* __restrict__ ceid){
  int e = blockIdx.x * 256 + threadIdx.x;
  if (e < NE){
    int d = eidx[NE + e];
    int pos = atomicAdd(&fill[d], 1);
    csrc[pos] = eidx[e];
    ceid[pos] = e;
  }
}
__global__ void k_fill_self(int* __restrict__ fill, int* __restrict__ csrc, int* __restrict__ ceid){
  int i = blockIdx.x * 256 + threadIdx.x;
  if (i < NN){
    int pos = atomicAdd(&fill[i], 1);
    csrc[pos] = i;
    ceid[pos] = NE;  // sentinel: mean edge-attr row
  }
}

// ---------------- fused GATv2 score + softmax aggregation + silu ----------------
// wave per node, 2 dims/lane (packed fp32), online softmax, DPP wave-sum.
__global__ __launch_bounds__(256) void k_sagg(const float* __restrict__ xlr,
    const float* __restrict__ ea, const float* __restrict__ eamean,
    const float* __restrict__ Wel, const float* __restrict__ attl, const float* __restrict__ gbl,
    const int* __restrict__ row_ptr, const int* __restrict__ csrc, const int* __restrict__ ceid,
    float* __restrict__ y){
  int t = threadIdx.x;
  int wid = t >> 6, lane = t & 63;
  int i = blockIdx.x * 4 + wid;
  if (i >= NN) return;
  int dim = lane << 1;
  pf2 rW[16];
  #pragma unroll
  for (int k = 0; k < 16; k++) rW[k] = *(const pf2*)(Wel + k * H + dim);
  pf2 xr2 = *(const pf2*)(xlr + (size_t)i * 256 + H + dim);
  pf2 a2 = *(const pf2*)(attl + dim);
  int row = __builtin_amdgcn_readfirstlane(row_ptr[i]);
  int end = __builtin_amdgcn_readfirstlane(row_ptr[i + 1]);
  float m = -1e30f, den = 0.f;
  pf2 acc2; acc2.x = 0.f; acc2.y = 0.f;
  for (int p = row; p < end; ++p){
    int s   = __builtin_amdgcn_readfirstlane(csrc[p]);
    int eid = __builtin_amdgcn_readfirstlane(ceid[p]);
    pf2 vl = *(const pf2*)(xlr + (size_t)s * 256 + dim);
    const float* ep = (eid < NE) ? (ea + (size_t)eid * 16) : eamean;
    pf2 ew; ew.x = 0.f; ew.y = 0.f;
    #pragma unroll
    for (int k = 0; k < 16; k++) ew += rW[k] * ep[k];
    pf2 vv = vl + xr2 + ew;
    pf2 vn = vv * NEG;
    vv.x = fmaxf(vv.x, vn.x);
    vv.y = fmaxf(vv.y, vn.y);
    pf2 sp = a2 * vv;
    float sc = wsum_bcast(sp.x + sp.y);
    if (sc <= m){
      float wv = __expf(sc - m);
      den += wv;
      acc2 += vl * wv;
    } else {
      float scale = __expf(m - sc);
      den = den * scale + 1.f;
      acc2 = acc2 * scale + vl;
      m = sc;
    }
  }
  float inv = 1.f / (den + 1e-16f);
  pf2 gb2 = *(const pf2*)(gbl + dim);
  pf2 o = acc2 * inv + gb2;
  o.x = siluf(o.x); o.y = siluf(o.y);
  *(pf2*)(y + (size_t)i * H + dim) = o;
}

extern "C" void kernel_launch(void* const* d_in, const int* in_sizes, int n_in,
                              void* d_out, int out_size, void* d_ws, size_t ws_size,
                              hipStream_t stream){
  (void)in_sizes; (void)n_in; (void)out_size; (void)ws_size;
  const float* x_t  = (const float*)d_in[0];
  const int*   t    = (const int*)d_in[1];
  const float* hf   = (const float*)d_in[2];
  const int*   eidx = (const int*)d_in[3];
  const float* ea   = (const float*)d_in[4];
  const int*   batch= (const int*)d_in[5];
  const float* tW1  = (const float*)d_in[6];
  const float* tb1  = (const float*)d_in[7];
  const float* tW2  = (const float*)d_in[8];
  const float* tb2  = (const float*)d_in[9];
  const float* hW1  = (const float*)d_in[10];
  const float* hb1  = (const float*)d_in[11];
  const float* hg1  = (const float*)d_in[12];
  const float* hB1  = (const float*)d_in[13];
  const float* hW2  = (const float*)d_in[14];
  const float* hb2  = (const float*)d_in[15];
  const float* hg2  = (const float*)d_in[16];
  const float* hB2  = (const float*)d_in[17];
  const float* Wl   = (const float*)d_in[18];
  const float* bl   = (const float*)d_in[19];
  const float* Wr   = (const float*)d_in[20];
  const float* br   = (const float*)d_in[21];
  const float* We   = (const float*)d_in[22];
  const float* att  = (const float*)d_in[23];
  const float* gb   = (const float*)d_in[24];
  const float* fcpW = (const float*)d_in[25];
  const float* fcpb = (const float*)d_in[26];
  const float* npW1 = (const float*)d_in[27];
  const float* npb1 = (const float*)d_in[28];
  const float* npg  = (const float*)d_in[29];
  const float* npB  = (const float*)d_in[30];
  const float* npW2 = (const float*)d_in[31];
  const float* npb2 = (const float*)d_in[32];

  char* w = (char*)d_ws;
  size_t off = 0;
  auto alloc = [&](size_t bytes) -> void* {
    void* p = w + off;
    off += (bytes + 255) & ~(size_t)255;
    return p;
  };
  float* table = (float*)alloc((size_t)1000 * H * 4);
  float* hbuf  = (float*)alloc((size_t)NB * H * 4);
  float* T0    = (float*)alloc((size_t)1000 * 256 * 4);
  float* H0b   = (float*)alloc((size_t)NB * 256 * 4);
  float* W0h   = (float*)alloc((size_t)32 * 256 * 4);
  float* W0m   = (float*)alloc((size_t)128 * 256 * 4);
  float* W0t   = (float*)alloc((size_t)128 * 256 * 4);
  float* b0    = (float*)alloc(256 * 4);
  float* Wp1   = (float*)alloc((size_t)288 * 256 * 4);
  float* Wp2   = (float*)alloc((size_t)288 * 256 * 4);
  float* Ac1   = (float*)alloc((size_t)128 * 256 * 4);
  float* Ac2   = (float*)alloc((size_t)128 * 256 * 4);
  float* cc1   = (float*)alloc(256 * 4);
  float* cc2   = (float*)alloc(256 * 4);
  float* eam   = (float*)alloc(16 * 4);
  int* deg     = (int*)alloc((size_t)NN * 4);
  int* row_ptr = (int*)alloc((size_t)(NN + 1) * 4);
  int* fill    = (int*)alloc((size_t)NN * 4);
  int* bs      = (int*)alloc(64 * 4);
  int* csrc    = (int*)alloc((size_t)ETOT * 4);
  int* ceid    = (int*)alloc((size_t)ETOT * 4);
  float* xlr   = (float*)alloc((size_t)NN * 256 * 4);
  float* y     = (float*)alloc((size_t)NN * H * 4);
  float* z2 = xlr;                      // reuse (free at nodeproj time)

  hipMemsetAsync(eam, 0, 64, stream);
  hipMemsetAsync(deg, 0, (size_t)NN * 4, stream);
  k_edge_mean<<<512, 256, 0, stream>>>(ea, eam);
  k_small<<<3, 256, 0, stream>>>(bl, br, Wl, Wr, fcpb, b0, cc1, cc2, eam);
  k_house<<<NB, 128, 0, stream>>>(hf, hW1, hb1, hg1, hB1, hW2, hb2, hg2, hB2, hbuf);
  k_temb<<<1000, 128, 0, stream>>>(tW1, tb1, tW2, tb2, table);
  // CSR build
  k_deg_count<<<(NE + 255) / 256, 256, 0, stream>>>(eidx, deg);
  k_scan1<<<49, 256, 0, stream>>>(deg, row_ptr, bs);
  k_scan2<<<1, 64, 0, stream>>>(bs, 49);
  k_scan3<<<(NN + 255) / 256, 256, 0, stream>>>(row_ptr, bs, deg, fill);
  k_fill_edges<<<(NE + 255) / 256, 256, 0, stream>>>(eidx, fill, csrc, ceid);
  k_fill_self<<<(NN + 255) / 256, 256, 0, stream>>>(fill, csrc, ceid);
  // weight packing + folded precomputes
  k_packs<<<dim3(288, 3), 256, 0, stream>>>(Wl, Wr, W0h, W0m, W0t, Wp1, Wp2);
  auto gemm = [&](const float* A, const float* W_, const float* bias, float* C, int M, int K, int Nc){
    dim3 g((M + 63) / 64, (Nc + 63) / 64);
    k_gemm<<<g, 256, 0, stream>>>(A, W_, bias, C, M, K, Nc);
  };
  auto gemm128 = [&](const float* A, const float* W_, const float* bias, float* C, int M, int K, int Nc){
    dim3 g((M + 127) / 128, (Nc + 127) / 128);
    k_gemm128<<<g, 256, 0, stream>>>(A, W_, bias, C, M, K, Nc);
  };
  gemm128(table, W0m, nullptr, T0, 1000, H, 256);
  gemm128(hbuf, W0t, nullptr, H0b, NB, H, 256);
  gemm(fcpW, Wp1, nullptr, Ac1, H, 288, 256);
  gemm(fcpW, Wp2, nullptr, Ac2, H, 288, 256);
  // ---- layer 0 ----
  k_xlr0<<<(NN + 3) / 4, 256, 0, stream>>>(x_t, t, batch, T0, H0b, W0h, b0, xlr);
  k_sagg<<<(NN + 3) / 4, 256, 0, stream>>>(xlr, ea, eam, We, att, gb, row_ptr, csrc, ceid, y);
  // ---- layer 1 (fc_projection folded into A,c) ----
  gemm128(y, Ac1, cc1, xlr, NN, H, 256);
  k_sagg<<<(NN + 3) / 4, 256, 0, stream>>>(xlr, ea, eam, We + 16 * H, att + H, gb + H, row_ptr, csrc, ceid, y);
  // ---- layer 2 ----
  gemm128(y, Ac2, cc2, xlr, NN, H, 256);
  k_sagg<<<(NN + 3) / 4, 256, 0, stream>>>(xlr, ea, eam, We + 32 * H, att + 2 * H, gb + 2 * H, row_ptr, csrc, ceid, y);
  // ---- node projection: GEMM + LN + SiLU fused, then final GEMM ----
  k_gemmln<<<(NN + 127) / 128, 256, 0, stream>>>(y, npW1, npb1, npg, npB, z2, NN);
  gemm(z2, npW2, npb2, (float*)d_out, NN, H, ND);
}

// Round 8
// 950.070 us; speedup vs baseline: 1.1146x; 1.0095x over previous
//
#include <hip/hip_runtime.h>
#include <hip/hip_bf16.h>

#define NN 50000
#define NE 800000
#define NB 5000
#define ND 32
#define EDD 16
#define HDD 64
#define H 128
#define ETOT (NE + NN)
#define NEG 0.2f
#define EPS_LN 1e-5f

typedef float pf2 __attribute__((ext_vector_type(2)));

__device__ __forceinline__ float siluf(float x){ return x / (1.f + __expf(-x)); }

__device__ __forceinline__ float wsum(float v){
  v += __shfl_xor(v, 32, 64);
  v += __shfl_xor(v, 16, 64);
  v += __shfl_xor(v, 8, 64);
  v += __shfl_xor(v, 4, 64);
  v += __shfl_xor(v, 2, 64);
  v += __shfl_xor(v, 1, 64);
  return v;
}

// DPP-based full-wave sum, result uniform (row_shr + bcast chain, readlane 63)
#define DPP_ADD(v, ctrl) \
  v += __builtin_bit_cast(float, __builtin_amdgcn_update_dpp(0, __builtin_bit_cast(int, v), ctrl, 0xf, 0xf, true))
__device__ __forceinline__ float wsum_bcast(float v){
  DPP_ADD(v, 0x111);  // row_shr:1
  DPP_ADD(v, 0x112);  // row_shr:2
  DPP_ADD(v, 0x114);  // row_shr:4
  DPP_ADD(v, 0x118);  // row_shr:8
  DPP_ADD(v, 0x142);  // row_bcast:15
  DPP_ADD(v, 0x143);  // row_bcast:31
  return __builtin_bit_cast(float, __builtin_amdgcn_readlane(__builtin_bit_cast(int, v), 63));
}

// ---------------- time embedding table ----------------
__global__ __launch_bounds__(128) void k_temb(const float* __restrict__ tW1, const float* __restrict__ tb1,
    const float* __restrict__ tW2, const float* __restrict__ tb2, float* __restrict__ table){
  __shared__ float smid[H];
  int bidx = blockIdx.x, j = threadIdx.x;
  float tv = (float)bidx;
  smid[j] = siluf(tv * tW1[j] + tb1[j]);
  __syncthreads();
  float acc = tb2[j];
  #pragma unroll
  for (int k = 0; k < H; k++) acc += smid[k] * tW2[k * H + j];
  table[bidx * H + j] = acc;
}

// ---------------- small fp32 tiled GEMM (64x64 tile) ----------------
__global__ __launch_bounds__(256) void k_gemm(const float* __restrict__ A, const float* __restrict__ W,
    const float* __restrict__ bias, float* __restrict__ C, int M, int K, int Nc){
  __shared__ float As[16][68];
  __shared__ float Ws[16][64];
  int t = threadIdx.x;
  int m0 = blockIdx.x * 64, n0 = blockIdx.y * 64;
  int tx = t & 15, ty = t >> 4;
  int la_m = t >> 2, la_k = (t & 3) << 2;
  int lw_k = t >> 4, lw_j = (t & 15) << 2;
  float acc[4][4] = {{0.f}};
  int arow = m0 + la_m;
  for (int k0 = 0; k0 < K; k0 += 16){
    float4 a = make_float4(0.f, 0.f, 0.f, 0.f);
    if (arow < M) a = *(const float4*)(A + (size_t)arow * K + k0 + la_k);
    As[la_k + 0][la_m] = a.x; As[la_k + 1][la_m] = a.y;
    As[la_k + 2][la_m] = a.z; As[la_k + 3][la_m] = a.w;
    float4 wv = make_float4(0.f, 0.f, 0.f, 0.f);
    if (n0 + lw_j < Nc) wv = *(const float4*)(W + (size_t)(k0 + lw_k) * Nc + n0 + lw_j);
    *(float4*)&Ws[lw_k][lw_j] = wv;
    __syncthreads();
    #pragma unroll
    for (int k = 0; k < 16; k++){
      float4 a4 = *(const float4*)&As[k][ty << 2];
      float4 b4 = *(const float4*)&Ws[k][tx << 2];
      acc[0][0] += a4.x * b4.x; acc[0][1] += a4.x * b4.y; acc[0][2] += a4.x * b4.z; acc[0][3] += a4.x * b4.w;
      acc[1][0] += a4.y * b4.x; acc[1][1] += a4.y * b4.y; acc[1][2] += a4.y * b4.z; acc[1][3] += a4.y * b4.w;
      acc[2][0] += a4.z * b4.x; acc[2][1] += a4.z * b4.y; acc[2][2] += a4.z * b4.z; acc[2][3] += a4.z * b4.w;
      acc[3][0] += a4.w * b4.x; acc[3][1] += a4.w * b4.y; acc[3][2] += a4.w * b4.z; acc[3][3] += a4.w * b4.w;
    }
    __syncthreads();
  }
  int col = n0 + (tx << 2);
  if (col < Nc){
    float4 b4 = make_float4(0.f, 0.f, 0.f, 0.f);
    if (bias) b4 = *(const float4*)(bias + col);
    #pragma unroll
    for (int r = 0; r < 4; r++){
      int row = m0 + (ty << 2) + r;
      if (row < M){
        float4 o = make_float4(acc[r][0] + b4.x, acc[r][1] + b4.y, acc[r][2] + b4.z, acc[r][3] + b4.w);
        *(float4*)(C + (size_t)row * Nc + col) = o;
      }
    }
  }
}

// ---------------- big fp32 GEMM: 128x128 tile, 8x8 micro, BK=16 ----------------
__global__ __launch_bounds__(256) void k_gemm128(const float* __restrict__ A, const float* __restrict__ W,
    const float* __restrict__ bias, float* __restrict__ C, int M, int K, int Nc){
  __shared__ float As[16][132];
  __shared__ float Ws[16][128];
  int t = threadIdx.x;
  int m0 = blockIdx.x * 128, n0 = blockIdx.y * 128;
  int tx = t & 15, ty = t >> 4;
  float acc[8][8];
  #pragma unroll
  for (int r = 0; r < 8; r++)
    #pragma unroll
    for (int c = 0; c < 8; c++) acc[r][c] = 0.f;
  for (int k0 = 0; k0 < K; k0 += 16){
    #pragma unroll
    for (int l = 0; l < 2; l++){
      int idx = t + l * 256;
      int ar = idx >> 2, ac = (idx & 3) << 2;
      float4 a = make_float4(0.f, 0.f, 0.f, 0.f);
      if (m0 + ar < M) a = *(const float4*)(A + (size_t)(m0 + ar) * K + k0 + ac);
      As[ac + 0][ar] = a.x; As[ac + 1][ar] = a.y;
      As[ac + 2][ar] = a.z; As[ac + 3][ar] = a.w;
    }
    #pragma unroll
    for (int l = 0; l < 2; l++){
      int idx = t + l * 256;
      int wr = idx >> 5, wc = (idx & 31) << 2;
      float4 wv = make_float4(0.f, 0.f, 0.f, 0.f);
      if (n0 + wc < Nc) wv = *(const float4*)(W + (size_t)(k0 + wr) * Nc + n0 + wc);
      *(float4*)&Ws[wr][wc] = wv;
    }
    __syncthreads();
    #pragma unroll
    for (int k = 0; k < 16; k++){
      float4 a0 = *(const float4*)&As[k][ty * 8];
      float4 a1 = *(const float4*)&As[k][ty * 8 + 4];
      float4 b0 = *(const float4*)&Ws[k][tx * 8];
      float4 b1 = *(const float4*)&Ws[k][tx * 8 + 4];
      float ar_[8] = {a0.x, a0.y, a0.z, a0.w, a1.x, a1.y, a1.z, a1.w};
      float bc_[8] = {b0.x, b0.y, b0.z, b0.w, b1.x, b1.y, b1.z, b1.w};
      #pragma unroll
      for (int r = 0; r < 8; r++)
        #pragma unroll
        for (int c = 0; c < 8; c++) acc[r][c] += ar_[r] * bc_[c];
    }
    __syncthreads();
  }
  int col = n0 + tx * 8;
  float4 bb0 = make_float4(0.f, 0.f, 0.f, 0.f), bb1 = bb0;
  if (bias && col < Nc){ bb0 = *(const float4*)(bias + col); bb1 = *(const float4*)(bias + col + 4); }
  #pragma unroll
  for (int r = 0; r < 8; r++){
    int row = m0 + ty * 8 + r;
    if (row < M && col < Nc){
      float4 o0 = make_float4(acc[r][0] + bb0.x, acc[r][1] + bb0.y, acc[r][2] + bb0.z, acc[r][3] + bb0.w);
      float4 o1 = make_float4(acc[r][4] + bb1.x, acc[r][5] + bb1.y, acc[r][6] + bb1.z, acc[r][7] + bb1.w);
      *(float4*)(C + (size_t)row * Nc + col) = o0;
      *(float4*)(C + (size_t)row * Nc + col + 4) = o1;
    }
  }
}

// ---------------- GEMM (M x K x 128) fused with LayerNorm + SiLU epilogue ----------------
__global__ __launch_bounds__(256) void k_gemmln(const float* __restrict__ A, const float* __restrict__ W,
    const float* __restrict__ bias, const float* __restrict__ g, const float* __restrict__ B,
    float* __restrict__ out, int M, int K){
  __shared__ float As[16][132];
  __shared__ float Ws[16][128];
  int t = threadIdx.x;
  int m0 = blockIdx.x * 128;
  int tx = t & 15, ty = t >> 4;
  float acc[8][8];
  #pragma unroll
  for (int r = 0; r < 8; r++)
    #pragma unroll
    for (int c = 0; c < 8; c++) acc[r][c] = 0.f;
  for (int k0 = 0; k0 < K; k0 += 16){
    #pragma unroll
    for (int l = 0; l < 2; l++){
      int idx = t + l * 256;
      int ar = idx >> 2, ac = (idx & 3) << 2;
      float4 a = make_float4(0.f, 0.f, 0.f, 0.f);
      if (m0 + ar < M) a = *(const float4*)(A + (size_t)(m0 + ar) * K + k0 + ac);
      As[ac + 0][ar] = a.x; As[ac + 1][ar] = a.y;
      As[ac + 2][ar] = a.z; As[ac + 3][ar] = a.w;
    }
    #pragma unroll
    for (int l = 0; l < 2; l++){
      int idx = t + l * 256;
      int wr = idx >> 5, wc = (idx & 31) << 2;
      *(float4*)&Ws[wr][wc] = *(const float4*)(W + (size_t)(k0 + wr) * H + wc);
    }
    __syncthreads();
    #pragma unroll
    for (int k = 0; k < 16; k++){
      float4 a0 = *(const float4*)&As[k][ty * 8];
      float4 a1 = *(const float4*)&As[k][ty * 8 + 4];
      float4 b0 = *(const float4*)&Ws[k][tx * 8];
      float4 b1 = *(const float4*)&Ws[k][tx * 8 + 4];
      float ar_[8] = {a0.x, a0.y, a0.z, a0.w, a1.x, a1.y, a1.z, a1.w};
      float bc_[8] = {b0.x, b0.y, b0.z, b0.w, b1.x, b1.y, b1.z, b1.w};
      #pragma unroll
      for (int r = 0; r < 8; r++)
        #pragma unroll
        for (int c = 0; c < 8; c++) acc[r][c] += ar_[r] * bc_[c];
    }
    __syncthreads();
  }
  int col = tx * 8;
  float bb[8], gv[8], Bv[8];
  *(float4*)&bb[0] = *(const float4*)(bias + col); *(float4*)&bb[4] = *(const float4*)(bias + col + 4);
  *(float4*)&gv[0] = *(const float4*)(g + col);    *(float4*)&gv[4] = *(const float4*)(g + col + 4);
  *(float4*)&Bv[0] = *(const float4*)(B + col);    *(float4*)&Bv[4] = *(const float4*)(B + col + 4);
  #pragma unroll
  for (int r = 0; r < 8; r++){
    int row = m0 + ty * 8 + r;
    if (row >= M) continue;   // uniform across the 16-lane shfl group
    float v[8];
    float s = 0.f;
    #pragma unroll
    for (int c = 0; c < 8; c++){ v[c] = acc[r][c] + bb[c]; s += v[c]; }
    s += __shfl_xor(s, 1, 16); s += __shfl_xor(s, 2, 16);
    s += __shfl_xor(s, 4, 16); s += __shfl_xor(s, 8, 16);
    float mu = s * 0.0078125f;
    float s2 = 0.f;
    #pragma unroll
    for (int c = 0; c < 8; c++){ v[c] -= mu; s2 += v[c] * v[c]; }
    s2 += __shfl_xor(s2, 1, 16); s2 += __shfl_xor(s2, 2, 16);
    s2 += __shfl_xor(s2, 4, 16); s2 += __shfl_xor(s2, 8, 16);
    float rstd = 1.f / sqrtf(s2 * 0.0078125f + EPS_LN);
    float o[8];
    #pragma unroll
    for (int c = 0; c < 8; c++) o[c] = siluf(v[c] * rstd * gv[c] + Bv[c]);
    *(float4*)(out + (size_t)row * H + col) = *(float4*)&o[0];
    *(float4*)(out + (size_t)row * H + col + 4) = *(float4*)&o[4];
  }
}

// ---------------- weight packing (all three layers in one launch) ----------------
__global__ void k_packs(const float* __restrict__ Wl, const float* __restrict__ Wr,
    float* __restrict__ W0h, float* __restrict__ W0m, float* __restrict__ W0t,
    float* __restrict__ Wp1, float* __restrict__ Wp2){
  int r = blockIdx.x, L = blockIdx.y, c = threadIdx.x;
  float v = (c < H) ? Wl[(size_t)L * 288 * H + r * H + c] : Wr[(size_t)L * 288 * H + r * H + (c - H)];
  if (L == 0){
    if (r < 32) W0h[r * 256 + c] = v;
    else if (r < 160) W0m[(r - 32) * 256 + c] = v;
    else W0t[(r - 160) * 256 + c] = v;
  } else {
    (L == 1 ? Wp1 : Wp2)[r * 256 + c] = v;
  }
}
// b0 assembly + eam scaling + folded cc vectors (reads Wl/Wr directly)
__global__ void k_small(const float* __restrict__ bl, const float* __restrict__ br,
    const float* __restrict__ Wl, const float* __restrict__ Wr, const float* __restrict__ fcpb,
    float* __restrict__ b0, float* __restrict__ cc1, float* __restrict__ cc2, float* __restrict__ eam){
  int c = threadIdx.x, which = blockIdx.x;
  if (which == 0){
    b0[c] = (c < H) ? bl[c] : br[c - H];
    if (c < 16) eam[c] *= (1.f / NE);
  } else {
    int cc = (c < H) ? c : c - H;
    const float* Wsrc = ((c < H) ? Wl : Wr) + (size_t)which * 288 * H;
    float acc = (c < H) ? bl[which * H + cc] : br[which * H + cc];
    for (int k = 0; k < 288; k++) acc += fcpb[k] * Wsrc[k * H + cc];
    (which == 1 ? cc1 : cc2)[c] = acc;
  }
}

// ---------------- layer 0 xl/xr assembly: 4 nodes/block, float4 per lane ----------------
__global__ __launch_bounds__(256) void k_xlr0(const float* __restrict__ x_t, const int* __restrict__ tt,
    const int* __restrict__ batch, const float* __restrict__ T0, const float* __restrict__ H0,
    const float* __restrict__ Whead, const float* __restrict__ b0, float* __restrict__ xlr){
  __shared__ float sx[4][ND];
  __shared__ int sti[4], sbi[4];
  int b4 = blockIdx.x * 4;
  int t = threadIdx.x;
  if (t < 128){
    int n = t >> 5, k = t & 31;
    int i = b4 + n;
    if (i < NN) sx[n][k] = x_t[(size_t)i * ND + k];
  }
  if (t < 4){
    int i = b4 + t;
    if (i < NN){ sti[t] = tt[i]; sbi[t] = batch[i]; }
  }
  __syncthreads();
  int wid = t >> 6, lane = t & 63;
  int i = b4 + wid;
  if (i >= NN) return;
  int c = lane << 2;
  float4 acc = *(const float4*)(b0 + c);
  float4 tv = *(const float4*)(T0 + (size_t)sti[wid] * 256 + c);
  float4 hv = *(const float4*)(H0 + (size_t)sbi[wid] * 256 + c);
  acc.x += tv.x + hv.x; acc.y += tv.y + hv.y; acc.z += tv.z + hv.z; acc.w += tv.w + hv.w;
  #pragma unroll
  for (int k = 0; k < ND; k++){
    float xk = sx[wid][k];
    float4 wv = *(const float4*)(Whead + k * 256 + c);
    acc.x += xk * wv.x; acc.y += xk * wv.y; acc.z += xk * wv.z; acc.w += xk * wv.w;
  }
  *(float4*)(xlr + (size_t)i * 256 + c) = acc;
}

// ---------------- edge-attr mean ----------------
__global__ void k_edge_mean(const float* __restrict__ ea, float* __restrict__ sum16){
  __shared__ float ss[16];
  int t = threadIdx.x;
  if (t < 16) ss[t] = 0.f;
  __syncthreads();
  float p[16];
  #pragma unroll
  for (int k = 0; k < 16; k++) p[k] = 0.f;
  for (int r = blockIdx.x * blockDim.x + t; r < NE; r += gridDim.x * blockDim.x){
    const float4* rp = (const float4*)(ea + (size_t)r * 16);
    float4 q0 = rp[0], q1 = rp[1], q2 = rp[2], q3 = rp[3];
    p[0] += q0.x; p[1] += q0.y; p[2] += q0.z; p[3] += q0.w;
    p[4] += q1.x; p[5] += q1.y; p[6] += q1.z; p[7] += q1.w;
    p[8] += q2.x; p[9] += q2.y; p[10] += q2.z; p[11] += q2.w;
    p[12] += q3.x; p[13] += q3.y; p[14] += q3.z; p[15] += q3.w;
  }
  #pragma unroll
  for (int k = 0; k < 16; k++) atomicAdd(&ss[k], p[k]);
  __syncthreads();
  if (t < 16) atomicAdd(&sum16[t], ss[t]);
}

// ---------------- CSR build ----------------
__global__ void k_deg_count(const int* __restrict__ eidx, int* __restrict__ deg){
  int e = blockIdx.x * 256 + threadIdx.x;
  if (e < NE) atomicAdd(&deg[eidx[NE + e]], 1);
}
__global__ __launch_bounds__(256) void k_scan1(const int* __restrict__ deg, int* __restrict__ row_ptr, int* __restrict__ bs){
  __shared__ int sc[256];
  int t = threadIdx.x;
  int base = blockIdx.x * 1024 + t * 4;
  int v0 = (base + 0 < NN) ? deg[base + 0] + 1 : 0;   // +1 self loop
  int v1 = (base + 1 < NN) ? deg[base + 1] + 1 : 0;
  int v2 = (base + 2 < NN) ? deg[base + 2] + 1 : 0;
  int v3 = (base + 3 < NN) ? deg[base + 3] + 1 : 0;
  int s0 = v0, s1 = s0 + v1, s2 = s1 + v2, s3 = s2 + v3;
  sc[t] = s3;
  __syncthreads();
  for (int off = 1; off < 256; off <<= 1){
    int add = (t >= off) ? sc[t - off] : 0;
    __syncthreads();
    sc[t] += add;
    __syncthreads();
  }
  int excl = sc[t] - s3;
  if (base + 0 < NN) row_ptr[base + 1] = excl + s0;
  if (base + 1 < NN) row_ptr[base + 2] = excl + s1;
  if (base + 2 < NN) row_ptr[base + 3] = excl + s2;
  if (base + 3 < NN) row_ptr[base + 4] = excl + s3;
  if (t == 255) bs[blockIdx.x] = sc[255];
}
__global__ void k_scan2(int* __restrict__ bs, int nb){
  int lane = threadIdx.x;
  int v = (lane < nb) ? bs[lane] : 0;
  for (int off = 1; off < 64; off <<= 1){
    int n = __shfl_up(v, off, 64);
    if (lane >= off) v += n;
  }
  if (lane < nb) bs[lane] = v;
}
__global__ void k_scan3(int* __restrict__ row_ptr, const int* __restrict__ bs,
    const int* __restrict__ deg, int* __restrict__ fill){
  int i = blockIdx.x * 256 + threadIdx.x;
  if (i == 0) row_ptr[0] = 0;
  if (i < NN){
    int chunk = i >> 10;
    int rp1 = row_ptr[i + 1] + ((chunk > 0) ? bs[chunk - 1] : 0);
    row_ptr[i + 1] = rp1;
    fill[i] = rp1 - deg[i] - 1;   // = row_ptr[i]
  }
}
__global__ void k_fill_edges(const int* __restrict__ eidx, int* __restrict__ fill,
    int2* __restrict__ cse){
  int e = blockIdx.x * 256 + threadIdx.x;
  if (e < NE){
    int d = eidx[NE + e];
    int pos = atomicAdd(&fill[d], 1);
    cse[pos] = make_int2(eidx[e], e);
  }
}
__global__ void k_fill_self(int* __restrict__ fill, int2* __restrict__ cse){
  int i = blockIdx.x * 256 + threadIdx.x;
  if (i < NN){
    int pos = atomicAdd(&fill[i], 1);
    cse[pos] = make_int2(i, NE);  // sentinel: mean edge-attr row
  }
}

// ---------------- fused GATv2 score + softmax aggregation + silu ----------------
// wave per node, 2 dims/lane (packed fp32), TWO independent online-softmax states
// (edges p, p+1) merged at the end -> 2x memory-level parallelism + chain overlap.
__global__ __launch_bounds__(256) void k_sagg(const float* __restrict__ xlr,
    const float* __restrict__ ea, const float* __restrict__ eamean,
    const float* __restrict__ Wel, const float* __restrict__ attl, const float* __restrict__ gbl,
    const int* __restrict__ row_ptr, const int2* __restrict__ cse,
    float* __restrict__ y){
  int t = threadIdx.x;
  int wid = t >> 6, lane = t & 63;
  int i = blockIdx.x * 4 + wid;
  if (i >= NN) return;
  int dim = lane << 1;
  pf2 rW[16];
  #pragma unroll
  for (int k = 0; k < 16; k++) rW[k] = *(const pf2*)(Wel + k * H + dim);
  pf2 xr2 = *(const pf2*)(xlr + (size_t)i * 256 + H + dim);
  pf2 a2 = *(const pf2*)(attl + dim);
  int row = __builtin_amdgcn_readfirstlane(row_ptr[i]);
  int end = __builtin_amdgcn_readfirstlane(row_ptr[i + 1]);
  float m1 = -1e30f, den1 = 0.f;
  float m2 = -1e30f, den2 = 0.f;
  pf2 acc1; acc1.x = 0.f; acc1.y = 0.f;
  pf2 acc2; acc2.x = 0.f; acc2.y = 0.f;
  auto edge = [&](int p, float& m, float& den, pf2& acc){
    int2 se = cse[p];
    int s   = __builtin_amdgcn_readfirstlane(se.x);
    int eid = __builtin_amdgcn_readfirstlane(se.y);
    pf2 vl = *(const pf2*)(xlr + (size_t)s * 256 + dim);
    const float* ep = (eid < NE) ? (ea + (size_t)eid * 16) : eamean;
    pf2 ew; ew.x = 0.f; ew.y = 0.f;
    #pragma unroll
    for (int k = 0; k < 16; k++) ew += rW[k] * ep[k];
    pf2 vv = vl + xr2 + ew;
    pf2 vn = vv * NEG;
    vv.x = fmaxf(vv.x, vn.x);
    vv.y = fmaxf(vv.y, vn.y);
    pf2 sp = a2 * vv;
    float sc = wsum_bcast(sp.x + sp.y);
    if (sc <= m){
      float wv = __expf(sc - m);
      den += wv;
      acc += vl * wv;
    } else {
      float f = __expf(m - sc);
      den = den * f + 1.f;
      acc = acc * f + vl;
      m = sc;
    }
  };
  int p = row;
  for (; p + 1 < end; p += 2){
    edge(p, m1, den1, acc1);
    edge(p + 1, m2, den2, acc2);
  }
  if (p < end) edge(p, m1, den1, acc1);
  // merge the two states (f2 -> 0 if state2 empty)
  float M = fmaxf(m1, m2);
  float f1 = __expf(m1 - M), f2 = __expf(m2 - M);
  float den = den1 * f1 + den2 * f2;
  pf2 acc = acc1 * f1 + acc2 * f2;
  float inv = 1.f / (den + 1e-16f);
  pf2 gb2 = *(const pf2*)(gbl + dim);
  pf2 o = acc * inv + gb2;
  o.x = siluf(o.x); o.y = siluf(o.y);
  *(pf2*)(y + (size_t)i * H + dim) = o;
}

extern "C" void kernel_launch(void* const* d_in, const int* in_sizes, int n_in,
                              void* d_out, int out_size, void* d_ws, size_t ws_size,
                              hipStream_t stream){
  (void)in_sizes; (void)n_in; (void)out_size; (void)ws_size;
  const float* x_t  = (const float*)d_in[0];
  const int*   t    = (const int*)d_in[1];
  const float* hf   = (const float*)d_in[2];
  const int*   eidx = (const int*)d_in[3];
  const float* ea   = (const float*)d_in[4];
  const int*   batch= (const int*)d_in[5];
  const float* tW1  = (const float*)d_in[6];
  const float* tb1  = (const float*)d_in[7];
  const float* tW2  = (const float*)d_in[8];
  const float* tb2  = (const float*)d_in[9];
  const float* hW1  = (const float*)d_in[10];
  const float* hb1  = (const float*)d_in[11];
  const float* hg1  = (const float*)d_in[12];
  const float* hB1  = (const float*)d_in[13];
  const float* hW2  = (const float*)d_in[14];
  const float* hb2  = (const float*)d_in[15];
  const float* hg2  = (const float*)d_in[16];
  const float* hB2  = (const float*)d_in[17];
  const float* Wl   = (const float*)d_in[18];
  const float* bl   = (const float*)d_in[19];
  const float* Wr   = (const float*)d_in[20];
  const float* br   = (const float*)d_in[21];
  const float* We   = (const float*)d_in[22];
  const float* att  = (const float*)d_in[23];
  const float* gb   = (const float*)d_in[24];
  const float* fcpW = (const float*)d_in[25];
  const float* fcpb = (const float*)d_in[26];
  const float* npW1 = (const float*)d_in[27];
  const float* npb1 = (const float*)d_in[28];
  const float* npg  = (const float*)d_in[29];
  const float* npB  = (const float*)d_in[30];
  const float* npW2 = (const float*)d_in[31];
  const float* npb2 = (const float*)d_in[32];

  char* w = (char*)d_ws;
  size_t off = 0;
  auto alloc = [&](size_t bytes) -> void* {
    void* p = w + off;
    off += (bytes + 255) & ~(size_t)255;
    return p;
  };
  float* table = (float*)alloc((size_t)1000 * H * 4);
  float* hbuf1 = (float*)alloc((size_t)NB * H * 4);
  float* hbuf  = (float*)alloc((size_t)NB * H * 4);
  float* T0    = (float*)alloc((size_t)1000 * 256 * 4);
  float* H0b   = (float*)alloc((size_t)NB * 256 * 4);
  float* W0h   = (float*)alloc((size_t)32 * 256 * 4);
  float* W0m   = (float*)alloc((size_t)128 * 256 * 4);
  float* W0t   = (float*)alloc((size_t)128 * 256 * 4);
  float* b0    = (float*)alloc(256 * 4);
  float* Wp1   = (float*)alloc((size_t)288 * 256 * 4);
  float* Wp2   = (float*)alloc((size_t)288 * 256 * 4);
  float* Ac1   = (float*)alloc((size_t)128 * 256 * 4);
  float* Ac2   = (float*)alloc((size_t)128 * 256 * 4);
  float* cc1   = (float*)alloc(256 * 4);
  float* cc2   = (float*)alloc(256 * 4);
  float* eam   = (float*)alloc(16 * 4);
  int* deg     = (int*)alloc((size_t)NN * 4);
  int* row_ptr = (int*)alloc((size_t)(NN + 1) * 4);
  int* fill    = (int*)alloc((size_t)NN * 4);
  int* bs      = (int*)alloc(64 * 4);
  int2* cse    = (int2*)alloc((size_t)ETOT * 8);
  float* xlr   = (float*)alloc((size_t)NN * 256 * 4);
  float* y     = (float*)alloc((size_t)NN * H * 4);
  float* z2 = xlr;                      // reuse (free at nodeproj time)

  hipMemsetAsync(eam, 0, 64, stream);
  hipMemsetAsync(deg, 0, (size_t)NN * 4, stream);
  k_edge_mean<<<512, 256, 0, stream>>>(ea, eam);
  k_small<<<3, 256, 0, stream>>>(bl, br, Wl, Wr, fcpb, b0, cc1, cc2, eam);
  // household encoder via fused GEMM+LN+SiLU (two stages)
  k_gemmln<<<(NB + 127) / 128, 256, 0, stream>>>(hf, hW1, hb1, hg1, hB1, hbuf1, NB, HDD);
  k_gemmln<<<(NB + 127) / 128, 256, 0, stream>>>(hbuf1, hW2, hb2, hg2, hB2, hbuf, NB, H);
  k_temb<<<1000, 128, 0, stream>>>(tW1, tb1, tW2, tb2, table);
  // CSR build
  k_deg_count<<<(NE + 255) / 256, 256, 0, stream>>>(eidx, deg);
  k_scan1<<<49, 256, 0, stream>>>(deg, row_ptr, bs);
  k_scan2<<<1, 64, 0, stream>>>(bs, 49);
  k_scan3<<<(NN + 255) / 256, 256, 0, stream>>>(row_ptr, bs, deg, fill);
  k_fill_edges<<<(NE + 255) / 256, 256, 0, stream>>>(eidx, fill, cse);
  k_fill_self<<<(NN + 255) / 256, 256, 0, stream>>>(fill, cse);
  // weight packing + folded precomputes
  k_packs<<<dim3(288, 3), 256, 0, stream>>>(Wl, Wr, W0h, W0m, W0t, Wp1, Wp2);
  auto gemm = [&](const float* A, const float* W_, const float* bias, float* C, int M, int K, int Nc){
    dim3 g((M + 63) / 64, (Nc + 63) / 64);
    k_gemm<<<g, 256, 0, stream>>>(A, W_, bias, C, M, K, Nc);
  };
  auto gemm128 = [&](const float* A, const float* W_, const float* bias, float* C, int M, int K, int Nc){
    dim3 g((M + 127) / 128, (Nc + 127) / 128);
    k_gemm128<<<g, 256, 0, stream>>>(A, W_, bias, C, M, K, Nc);
  };
  gemm128(table, W0m, nullptr, T0, 1000, H, 256);
  gemm128(hbuf, W0t, nullptr, H0b, NB, H, 256);
  gemm(fcpW, Wp1, nullptr, Ac1, H, 288, 256);
  gemm(fcpW, Wp2, nullptr, Ac2, H, 288, 256);
  // ---- layer 0 ----
  k_xlr0<<<(NN + 3) / 4, 256, 0, stream>>>(x_t, t, batch, T0, H0b, W0h, b0, xlr);
  k_sagg<<<(NN + 3) / 4, 256, 0, stream>>>(xlr, ea, eam, We, att, gb, row_ptr, cse, y);
  // ---- layer 1 (fc_projection folded into A,c) ----
  gemm128(y, Ac1, cc1, xlr, NN, H, 256);
  k_sagg<<<(NN + 3) / 4, 256, 0, stream>>>(xlr, ea, eam, We + 16 * H, att + H, gb + H, row_ptr, cse, y);
  // ---- layer 2 ----
  gemm128(y, Ac2, cc2, xlr, NN, H, 256);
  k_sagg<<<(NN + 3) / 4, 256, 0, stream>>>(xlr, ea, eam, We + 32 * H, att + 2 * H, gb + 2 * H, row_ptr, cse, y);
  // ---- node projection: GEMM + LN + SiLU fused, then final GEMM ----
  k_gemmln<<<(NN + 127) / 128, 256, 0, stream>>>(y, npW1, npb1, npg, npB, z2, NN, H);
  gemm(z2, npW2, npb2, (float*)d_out, NN, H, ND);
}